// Round 1
// 156.518 us; speedup vs baseline: 1.0212x; 1.0212x over previous
//
#include <hip/hip_runtime.h>
#include <hip/hip_bf16.h>
#include <cstddef>
#include <cstdint>

// JastrowNet, two kernels.
// K1 (filters), MFMA version: the 32->16->8 ssp MLP is two mfma_f32_16x16x32_bf16
//   per 16-row tile using the swapped-operand trick:
//     D1 = W1^T(16x32) x rows^T(32x16)   -> lane holds h1 for (hidden=(l>>4)*4+r, row=l&15)
//     ssp -> pack bf16 -> 4 x shfl       -> B2 frag (k=(l>>4)*8+e contiguous, zero k>=16)
//     D2 = W2^T(16x32, zero-padded) x B2 -> lane holds out for (k_out=(l>>4)*4+r, row=l&15)
//   Biases enter as the MFMA C operand. Layer-1 output reduced in-wave to z1 partials
//   (hx1 is spin-only); layer-2 elec filters stored masked bf16; nuclear filters
//   pre-reduced against Y for both layers. No LDS, no __syncthreads.
// K2 (update): unchanged from previous version.
//
// Workspace layout (bytes):
//   [0, 8388608)            w2 : bf16 [512][32][32][8]
//   [8388608, +1048576)     z1p: f32 [512][2][32][8]  (partials over j-halves)
//   [+, +524288)            zn1: f32 [512][32][8]
//   [+, +524288)            zn2: f32 [512][32][8]

#define NB   512
#define NE   32
#define NA   8
#define NF   32
#define NH   16
#define NK   8
#define NEMB 16

typedef __attribute__((ext_vector_type(8))) short short8;
typedef __attribute__((ext_vector_type(4))) float f32x4;

__device__ __forceinline__ float ssp(float v){
    return fmaxf(v, 0.f) + __logf(1.f + __expf(-fabsf(v))) - 0.6931471805599453f;
}

// fp32 -> bf16 bits, round-to-nearest-even (finite inputs)
__device__ __forceinline__ short f2bf(float x){
    unsigned b = __float_as_uint(x);
    b += 0x7fffu + ((b >> 16) & 1u);
    return (short)(b >> 16);
}
__device__ __forceinline__ unsigned packbf2(float lo, float hi){
    return (unsigned)(unsigned short)f2bf(lo) | ((unsigned)(unsigned short)f2bf(hi) << 16);
}

// ---------------- K1: filters (MFMA) ----------------
// grid 2560: p = bid>>9 in [0,4]; p<4 -> elec quadrant (qi=p>>1, qj=p&1),
// p==4 -> nuclear. batch = bid & 511. 256 threads = 4 waves x 4 tiles of 16 rows.
extern "C" __global__ void __launch_bounds__(256, 4)
filters_kernel(const float* __restrict__ edges_elec,
               const float* __restrict__ edges_nuc,
               const float* __restrict__ X_emb,
               const float* __restrict__ Yk,
               const float* __restrict__ wW1, const float* __restrict__ wb1,
               const float* __restrict__ wW2, const float* __restrict__ wb2,
               const float* __restrict__ hW,  const float* __restrict__ hb,
               __hip_bfloat16* __restrict__ w2out,
               float* __restrict__ z1p,
               float* __restrict__ zn1, float* __restrict__ zn2)
{
    const int bid = blockIdx.x, t = threadIdx.x;
    const int p = bid >> 9, b = bid & 511;
    const bool isNuc = (p == 4);
    const int qi = p >> 1, qj = p & 1;
    const int cc = isNuc ? 2 : ((qi == qj) ? 0 : 1);

    const int lane = t & 63;
    const int r16 = lane & 15, g4 = lane >> 4;
    const int wq = (t >> 6) * 4;           // first 16-row tile index of this wave

    // ---- per-lane weight fragments (A operands, transposed layout) ----
    // A1[l]: lane holds W1[f=(g4*8+e)][h=r16]         (16x32, all valid)
    // A2[l]: lane holds W2[h=(g4*8+e)][k=r16]         (16x32, zero for h>=16 or k>=8)
    short8 a1[2], a2[2];
    f32x4 c1[2], c2[2];
#pragma unroll
    for (int l = 0; l < 2; l++){
        const float* W1 = wW1 + (size_t)(l*3 + cc)*NF*NH;
        const float* W2 = wW2 + (size_t)(l*3 + cc)*NH*NK;
        short8 s, s2;
#pragma unroll
        for (int e = 0; e < 8; e++){
            s[e] = f2bf(W1[(g4*8 + e)*NH + r16]);
            const int h = g4*8 + e;
            s2[e] = (h < NH && r16 < NK) ? f2bf(W2[h*NK + r16]) : (short)0;
        }
        a1[l] = s;
        a2[l] = s2;
        const float* B1 = wb1 + (l*3 + cc)*NH;
        const float* B2 = wb2 + (l*3 + cc)*NK;
        f32x4 cb1, cb2;
#pragma unroll
        for (int r = 0; r < 4; r++){
            const int m = g4*4 + r;
            cb1[r] = B1[m];
            cb2[r] = (m < NK) ? B2[m] : 0.f;
        }
        c1[l] = cb1; c2[l] = cb2;
    }

    // hx1[qj][k] (elec, spin-only) / Y[m][k] (nuc), k = g4*4+r (valid lanes g4<2)
    float hx[4] = {0.f,0.f,0.f,0.f};
    float Yv[4] = {0.f,0.f,0.f,0.f};
    if (!isNuc){
#pragma unroll
        for (int r = 0; r < 4; r++){
            const int kk = (g4*4 + r) & 7;   // clamp keeps OOB lanes in-bounds (unused)
            float acc = hb[kk];
#pragma unroll
            for (int e = 0; e < NEMB; e++)
                acc = fmaf(X_emb[qj*NEMB + e], hW[e*NK + kk], acc);
            hx[r] = ssp(acc);
        }
    } else {
        const int m = lane & 7;
#pragma unroll
        for (int r = 0; r < 4; r++)
            Yv[r] = Yk[m*NK + ((g4*4 + r) & 7)];
    }

    // ---- load the wave's 4 tiles of edge rows; B frag: row=r16, feats g4*8..+7 ----
    float4 rawA[4], rawB[4];
    if (!isNuc){
#pragma unroll
        for (int g = 0; g < 4; g++){
            const int i = qi*16 + wq + g;
            const float* src = edges_elec + (((size_t)b*NE + i)*NE + (qj*16 + r16))*NF + g4*8;
            rawA[g] = ((const float4*)src)[0];
            rawB[g] = ((const float4*)src)[1];
        }
    } else {
#pragma unroll
        for (int g = 0; g < 4; g++){
            const int gp = wq + g;
            const int i = 2*gp + (r16 >> 3), m = r16 & 7;
            const float* src = edges_nuc + (((size_t)b*NE + i)*NA + m)*NF + g4*8;
            rawA[g] = ((const float4*)src)[0];
            rawB[g] = ((const float4*)src)[1];
        }
    }
    short8 bfr[4];
#pragma unroll
    for (int g = 0; g < 4; g++){
        short8 s;
        s[0]=f2bf(rawA[g].x); s[1]=f2bf(rawA[g].y); s[2]=f2bf(rawA[g].z); s[3]=f2bf(rawA[g].w);
        s[4]=f2bf(rawB[g].x); s[5]=f2bf(rawB[g].y); s[6]=f2bf(rawB[g].z); s[7]=f2bf(rawB[g].w);
        bfr[g] = s;
    }

    // B2-frag gather lanes: dst lane (g4,r16) takes h1 columns from lanes
    // 2*g4*16 + r16 (hidden 8g..8g+3) and +16 (hidden 8g+4..8g+7)
    const int s0 = (g4*32 + r16) & 63;
    const int s1 = (g4*32 + 16 + r16) & 63;

#pragma unroll
    for (int g = 0; g < 4; g++){
#pragma unroll
        for (int l = 0; l < 2; l++){
            // MLP layer 1: D1[hidden][row] = W1^T x rows^T + b1
            f32x4 d1 = __builtin_amdgcn_mfma_f32_16x16x32_bf16(a1[l], bfr[g], c1[l], 0, 0, 0);
            const unsigned p0 = packbf2(ssp(d1[0]), ssp(d1[1]));
            const unsigned p1 = packbf2(ssp(d1[2]), ssp(d1[3]));
            unsigned q0 = __shfl(p0, s0, 64);
            unsigned q1 = __shfl(p1, s0, 64);
            unsigned q2 = __shfl(p0, s1, 64);
            unsigned q3 = __shfl(p1, s1, 64);
            if (g4 >= 2){ q0 = 0u; q1 = 0u; q2 = 0u; q3 = 0u; }   // k >= 16 pad
            union { unsigned u[4]; short8 v; } bb;
            bb.u[0]=q0; bb.u[1]=q1; bb.u[2]=q2; bb.u[3]=q3;
            // MLP layer 2: D2[k_out][row] = W2^T x h1^T + b2 (K padded 16->32)
            f32x4 d2 = __builtin_amdgcn_mfma_f32_16x16x32_bf16(a2[l], bb.v, c2[l], 0, 0, 0);
            float wk[4];
#pragma unroll
            for (int r = 0; r < 4; r++) wk[r] = ssp(d2[r]);

            if (!isNuc){
                const int i16 = wq + g;
                if (cc == 0 && r16 == i16){       // same-spin: exclude j == i
#pragma unroll
                    for (int r = 0; r < 4; r++) wk[r] = 0.f;
                }
                if (l == 0){
                    // z1 partial: sum over j (= r16), then scale by hx1[qj][k]
#pragma unroll
                    for (int off = 1; off < 16; off <<= 1)
#pragma unroll
                        for (int r = 0; r < 4; r++) wk[r] += __shfl_xor(wk[r], off, 64);
                    if (r16 == 0 && g4 < 2){
                        const int i = qi*16 + i16;
                        float4 st;
                        st.x = wk[0]*hx[0]; st.y = wk[1]*hx[1];
                        st.z = wk[2]*hx[2]; st.w = wk[3]*hx[3];
                        *(float4*)&z1p[(((size_t)b*2 + qj)*NE + i)*NK + g4*4] = st;
                    }
                } else if (g4 < 2){
                    // store masked layer-2 filter, bf16 [b][i][j][k]
                    const int i = qi*16 + i16, j = qj*16 + r16;
                    uint2 uu;
                    uu.x = packbf2(wk[0], wk[1]);
                    uu.y = packbf2(wk[2], wk[3]);
                    *(uint2*)&w2out[(((size_t)b*NE + i)*NE + j)*NK + g4*4] = uu;
                }
            } else {
                // nuclear: multiply by Y[m][k] and reduce over m (= lane&7)
#pragma unroll
                for (int r = 0; r < 4; r++) wk[r] *= Yv[r];
#pragma unroll
                for (int off = 1; off < 8; off <<= 1)
#pragma unroll
                    for (int r = 0; r < 4; r++) wk[r] += __shfl_xor(wk[r], off, 64);
                if ((r16 & 7) == 0 && g4 < 2){
                    const int i = 2*(wq + g) + (r16 >> 3);
                    float* dst = (l == 0) ? zn1 : zn2;
                    float4 st; st.x = wk[0]; st.y = wk[1]; st.z = wk[2]; st.w = wk[3];
                    *(float4*)&dst[((size_t)b*NE + i)*NK + g4*4] = st;
                }
            }
        }
    }
}

// ---------------- K2: per-batch sequential update (unchanged) ----------------
extern "C" __global__ void __launch_bounds__(256, 4)
update_kernel(const float* __restrict__ X_emb,
              const float* __restrict__ hW,  const float* __restrict__ hb,
              const float* __restrict__ gW,  const float* __restrict__ gb,
              const float* __restrict__ orbW,
              const __hip_bfloat16* __restrict__ w2,
              const float* __restrict__ z1p,
              const float* __restrict__ zn1, const float* __restrict__ zn2,
              float* __restrict__ out)
{
    __shared__ float s_x[NE*NEMB];     // 512
    __shared__ float s_z[NE*NK];       // 256
    __shared__ float s_hx[NE*NK];      // 256
    __shared__ float s_gW[2*NK*NEMB];  // 256
    __shared__ float s_gb[2*NEMB];
    __shared__ float s_hW1[NEMB*NK];
    __shared__ float s_hb1[NK];
    __shared__ float s_orb[NEMB];
    __shared__ float s_red[4];

    const int b = blockIdx.x, t = threadIdx.x;

    s_gW[t] = gW[t];
    if (t < 2*NEMB)  s_gb[t]  = gb[t];
    if (t < NEMB*NK) s_hW1[t] = hW[NEMB*NK + t];
    if (t < NK)      s_hb1[t] = hb[NK + t];
    if (t < NEMB)    s_orb[t] = orbW[t];
    // z1[i,k] = partials(qj=0,1) + nuclear
    {
        const int i = t >> 3, k = t & 7;
        s_z[t] = z1p[(((size_t)b*2 + 0)*NE + i)*NK + k]
               + z1p[(((size_t)b*2 + 1)*NE + i)*NK + k]
               + zn1[((size_t)b*NE + i)*NK + k];
    }
    __syncthreads();
    // x1 = x0 + z1 @ gW0 + gb0
#pragma unroll
    for (int q = 0; q < 2; q++){
        const int idx = q*256 + t, i = idx >> 4, e = idx & 15;
        float acc = s_gb[e];
#pragma unroll
        for (int k = 0; k < NK; k++)
            acc = fmaf(s_z[i*NK + k], s_gW[k*NEMB + e], acc);
        s_x[idx] = X_emb[(i >> 4)*NEMB + e] + acc;
    }
    __syncthreads();
    // hx2 = ssp(x1 @ hW1 + hb1)
    {
        const int i = t >> 3, k = t & 7;
        float acc = s_hb1[k];
#pragma unroll
        for (int e = 0; e < NEMB; e++)
            acc = fmaf(s_x[i*NEMB + e], s_hW1[e*NK + k], acc);
        s_hx[t] = ssp(acc);
    }
    __syncthreads();
    // z2[i,k] = sum_j w2[i,j,k]*hx2[j,k]
    {
        const int i16 = t >> 4, j16 = t & 15;
#pragma unroll
        for (int qh = 0; qh < 2; qh++){
            const int i = qh*16 + i16;
            float zacc[NK];
#pragma unroll
            for (int k = 0; k < NK; k++) zacc[k] = 0.f;
#pragma unroll
            for (int qj = 0; qj < 2; qj++){
                const int j = qj*16 + j16;
                union { uint4 u; __hip_bfloat16 h[8]; } raw;
                raw.u = *(const uint4*)&w2[((size_t)b*NE*NE + i*NE + j)*NK];
                float pk[NK];
#pragma unroll
                for (int k = 0; k < NK; k++)
                    pk[k] = __bfloat162float(raw.h[k]) * s_hx[j*NK + k];
#pragma unroll
                for (int off = 8; off > 0; off >>= 1)
#pragma unroll
                    for (int k = 0; k < NK; k++) pk[k] += __shfl_down(pk[k], off, 16);
#pragma unroll
                for (int k = 0; k < NK; k++) zacc[k] += pk[k];
            }
            if (j16 == 0){
#pragma unroll
                for (int k = 0; k < NK; k++) s_z[i*NK + k] = zacc[k];
            }
        }
    }
    __syncthreads();
    { const int i = t >> 3, k = t & 7; s_z[t] += zn2[((size_t)b*NE + i)*NK + k]; }
    __syncthreads();
    // x2 = x1 + z2 @ gW1 + gb1
#pragma unroll
    for (int q = 0; q < 2; q++){
        const int idx = q*256 + t, i = idx >> 4, e = idx & 15;
        float acc = s_gb[NEMB + e];
#pragma unroll
        for (int k = 0; k < NK; k++)
            acc = fmaf(s_z[i*NK + k], s_gW[NK*NEMB + k*NEMB + e], acc);
        s_x[idx] += acc;
    }
    __syncthreads();
    // readout
    float part = (s_x[t] + s_x[t + 256]) * s_orb[t & 15];
#pragma unroll
    for (int off = 32; off > 0; off >>= 1) part += __shfl_down(part, off, 64);
    if ((t & 63) == 0) s_red[t >> 6] = part;
    __syncthreads();
    if (t == 0) out[b] = s_red[0] + s_red[1] + s_red[2] + s_red[3];
}

extern "C" void kernel_launch(void* const* d_in, const int* in_sizes, int n_in,
                              void* d_out, int out_size, void* d_ws, size_t ws_size,
                              hipStream_t stream)
{
    const float* edges_elec = (const float*)d_in[0];
    const float* edges_nuc  = (const float*)d_in[1];
    const float* X_emb      = (const float*)d_in[2];
    const float* Yk         = (const float*)d_in[3];
    const float* wW1        = (const float*)d_in[4];
    const float* wb1        = (const float*)d_in[5];
    const float* wW2        = (const float*)d_in[6];
    const float* wb2        = (const float*)d_in[7];
    const float* hW         = (const float*)d_in[8];
    const float* hb         = (const float*)d_in[9];
    const float* gW         = (const float*)d_in[10];
    const float* gb         = (const float*)d_in[11];
    const float* orbW       = (const float*)d_in[12];

    char* ws = (char*)d_ws;
    __hip_bfloat16* w2 = (__hip_bfloat16*)ws;                     // 8,388,608 B
    float* z1p = (float*)(ws + 8388608);                          // 1,048,576 B
    float* zn1 = (float*)(ws + 8388608 + 1048576);                //   524,288 B
    float* zn2 = (float*)(ws + 8388608 + 1048576 + 524288);       //   524,288 B

    filters_kernel<<<5*NB, 256, 0, stream>>>(
        edges_elec, edges_nuc, X_emb, Yk, wW1, wb1, wW2, wb2, hW, hb,
        w2, z1p, zn1, zn2);
    update_kernel<<<NB, 256, 0, stream>>>(
        X_emb, hW, hb, gW, gb, orbW, w2, z1p, zn1, zn2, (float*)d_out);
}

// Round 2
// 156.170 us; speedup vs baseline: 1.0235x; 1.0022x over previous
//
#include <hip/hip_runtime.h>
#include <hip/hip_bf16.h>
#include <cstddef>
#include <cstdint>

// JastrowNet fully fused: ONE kernel, one block (512 thr = 8 waves) per batch.
// Filters via two mfma_f32_16x16x32_bf16 per 16-row tile (swapped-operand
// trick, identical math to the previous passing kernel). Layer-2 filters live
// in LDS (16 KB) -- no HBM round-trip, no second launch. z1 partials and
// nuclear reductions also in LDS. After one barrier the per-batch sequential
// update (x1, hx2, z2, x2, readout) runs on the same block.
//
// Per-wave tile schedule (wid = 0..7):
//   cc=0 (same-spin): tiles tau = 4*wid..4*wid+3, tau=(qi<<4)|g, qj=qi
//   cc=1 (anti)     : same tau enumeration, qj=1-qi
//   cc=2 (nuclear)  : gp = 2*wid, 2*wid+1 (each tile = rows 2gp, 2gp+1 x 8 atoms)
// Workspace: unused.

#define NB   512
#define NE   32
#define NA   8
#define NF   32
#define NH   16
#define NK   8
#define NEMB 16

typedef __attribute__((ext_vector_type(8))) short short8;
typedef __attribute__((ext_vector_type(4))) float f32x4;

__device__ __forceinline__ float ssp(float v){
    return fmaxf(v, 0.f) + __logf(1.f + __expf(-fabsf(v))) - 0.6931471805599453f;
}

// fp32 -> bf16 bits, round-to-nearest-even (finite inputs)
__device__ __forceinline__ short f2bf(float x){
    unsigned b = __float_as_uint(x);
    b += 0x7fffu + ((b >> 16) & 1u);
    return (short)(b >> 16);
}
__device__ __forceinline__ unsigned packbf2(float lo, float hi){
    return (unsigned)(unsigned short)f2bf(lo) | ((unsigned)(unsigned short)f2bf(hi) << 16);
}
__device__ __forceinline__ short8 cvt_row(float4 a, float4 b){
    short8 s;
    s[0]=f2bf(a.x); s[1]=f2bf(a.y); s[2]=f2bf(a.z); s[3]=f2bf(a.w);
    s[4]=f2bf(b.x); s[5]=f2bf(b.y); s[6]=f2bf(b.z); s[7]=f2bf(b.w);
    return s;
}

extern "C" __global__ void __launch_bounds__(512, 4)
jastrow_kernel(const float* __restrict__ edges_elec,
               const float* __restrict__ edges_nuc,
               const float* __restrict__ X_emb,
               const float* __restrict__ Yk,
               const float* __restrict__ wW1, const float* __restrict__ wb1,
               const float* __restrict__ wW2, const float* __restrict__ wb2,
               const float* __restrict__ hW,  const float* __restrict__ hb,
               const float* __restrict__ gW,  const float* __restrict__ gb,
               const float* __restrict__ orbW,
               float* __restrict__ out)
{
    __shared__ __align__(16) __hip_bfloat16 s_w2[NE*NE*NK];  // 16384 B
    __shared__ __align__(16) float s_z1p[2*NE*NK];           //  2048 B
    __shared__ __align__(16) float s_zn1[NE*NK];             //  1024 B
    __shared__ __align__(16) float s_zn2[NE*NK];             //  1024 B
    __shared__ float s_hx1[2*NK];
    __shared__ float s_x[NE*NEMB];                           //  2048 B
    __shared__ float s_z[NE*NK];                             //  1024 B
    __shared__ float s_hx[NE*NK];                            //  1024 B
    __shared__ float s_red[8];

    const int b = blockIdx.x, t = threadIdx.x;
    const int wid = t >> 6, lane = t & 63;
    const int r16 = lane & 15, g4 = lane >> 4;

    // ---- hx1[s][k] = ssp(X_emb[s] @ hW[0] + hb[0]) (spin-only) ----
    if (t < 2*NK){
        const int s = t >> 3, k = t & 7;
        float acc = hb[k];
#pragma unroll
        for (int e = 0; e < NEMB; e++)
            acc = fmaf(X_emb[s*NEMB + e], hW[e*NK + k], acc);
        s_hx1[t] = ssp(acc);
    }
    __syncthreads();

    // B2-frag gather source lanes (verbatim from passing kernel)
    const int s0 = (g4*32 + r16) & 63;
    const int s1 = (g4*32 + 16 + r16) & 63;

    // per-channel A-operand fragment + bias build (verbatim layout)
    auto build = [&](int cc, short8* a1, short8* a2, f32x4* c1, f32x4* c2){
#pragma unroll
        for (int l = 0; l < 2; l++){
            const float* W1 = wW1 + (size_t)(l*3 + cc)*NF*NH;
            const float* W2 = wW2 + (size_t)(l*3 + cc)*NH*NK;
            short8 s, s2;
#pragma unroll
            for (int e = 0; e < 8; e++){
                s[e] = f2bf(W1[(g4*8 + e)*NH + r16]);
                const int h = g4*8 + e;
                s2[e] = (h < NH && r16 < NK) ? f2bf(W2[h*NK + r16]) : (short)0;
            }
            a1[l] = s; a2[l] = s2;
            const float* B1 = wb1 + (l*3 + cc)*NH;
            const float* B2 = wb2 + (l*3 + cc)*NK;
            f32x4 cb1, cb2;
#pragma unroll
            for (int r = 0; r < 4; r++){
                const int m = g4*4 + r;
                cb1[r] = B1[m];
                cb2[r] = (m < NK) ? B2[m] : 0.f;
            }
            c1[l] = cb1; c2[l] = cb2;
        }
    };

    // ---- electron channels: cc=0 same-spin, cc=1 anti ----
#pragma unroll
    for (int cc = 0; cc < 2; cc++){
        short8 a1[2], a2[2]; f32x4 c1[2], c2[2];
        build(cc, a1, a2, c1, c2);
#pragma unroll
        for (int u = 0; u < 4; u++){
            const int tau = wid*4 + u;
            const int qi = tau >> 4;
            const int qj = cc ? (1 - qi) : qi;
            const int g  = tau & 15;
            const int i  = qi*16 + g;
            const float* src = edges_elec
                + (((size_t)b*NE + i)*NE + qj*16 + r16)*NF + g4*8;
            const float4 ra = ((const float4*)src)[0];
            const float4 rb = ((const float4*)src)[1];
            const short8 bfr = cvt_row(ra, rb);
#pragma unroll
            for (int l = 0; l < 2; l++){
                f32x4 d1 = __builtin_amdgcn_mfma_f32_16x16x32_bf16(a1[l], bfr, c1[l], 0, 0, 0);
                const unsigned p0 = packbf2(ssp(d1[0]), ssp(d1[1]));
                const unsigned p1 = packbf2(ssp(d1[2]), ssp(d1[3]));
                unsigned q0 = __shfl(p0, s0, 64);
                unsigned q1 = __shfl(p1, s0, 64);
                unsigned q2 = __shfl(p0, s1, 64);
                unsigned q3 = __shfl(p1, s1, 64);
                if (g4 >= 2){ q0 = 0u; q1 = 0u; q2 = 0u; q3 = 0u; }
                union { unsigned u4[4]; short8 v; } bb;
                bb.u4[0]=q0; bb.u4[1]=q1; bb.u4[2]=q2; bb.u4[3]=q3;
                f32x4 d2 = __builtin_amdgcn_mfma_f32_16x16x32_bf16(a2[l], bb.v, c2[l], 0, 0, 0);
                float wk[4];
#pragma unroll
                for (int r = 0; r < 4; r++) wk[r] = ssp(d2[r]);
                if (cc == 0 && r16 == g){
#pragma unroll
                    for (int r = 0; r < 4; r++) wk[r] = 0.f;
                }
                if (l == 0){
                    // z1 partial: sum over j (=r16), scale by hx1[spin(j)=qj]
#pragma unroll
                    for (int off = 1; off < 16; off <<= 1)
#pragma unroll
                        for (int r = 0; r < 4; r++) wk[r] += __shfl_xor(wk[r], off, 64);
                    if (r16 == 0 && g4 < 2){
                        float4 st;
                        st.x = wk[0]*s_hx1[qj*NK + g4*4 + 0];
                        st.y = wk[1]*s_hx1[qj*NK + g4*4 + 1];
                        st.z = wk[2]*s_hx1[qj*NK + g4*4 + 2];
                        st.w = wk[3]*s_hx1[qj*NK + g4*4 + 3];
                        *(float4*)&s_z1p[(qj*NE + i)*NK + g4*4] = st;
                    }
                } else if (g4 < 2){
                    const int j = qj*16 + r16;
                    uint2 uu;
                    uu.x = packbf2(wk[0], wk[1]);
                    uu.y = packbf2(wk[2], wk[3]);
                    *(uint2*)&s_w2[(i*NE + j)*NK + g4*4] = uu;
                }
            }
        }
    }

    // ---- nuclear channel (cc=2) ----
    {
        short8 a1[2], a2[2]; f32x4 c1[2], c2[2];
        build(2, a1, a2, c1, c2);
        const int m = lane & 7;
        float Yv[4];
#pragma unroll
        for (int r = 0; r < 4; r++)
            Yv[r] = Yk[m*NK + ((g4*4 + r) & 7)];
#pragma unroll
        for (int u = 0; u < 2; u++){
            const int gp = wid*2 + u;
            const int i  = 2*gp + (r16 >> 3);
            const float* src = edges_nuc
                + (((size_t)b*NE + i)*NA + m)*NF + g4*8;
            const float4 ra = ((const float4*)src)[0];
            const float4 rb = ((const float4*)src)[1];
            const short8 bfr = cvt_row(ra, rb);
#pragma unroll
            for (int l = 0; l < 2; l++){
                f32x4 d1 = __builtin_amdgcn_mfma_f32_16x16x32_bf16(a1[l], bfr, c1[l], 0, 0, 0);
                const unsigned p0 = packbf2(ssp(d1[0]), ssp(d1[1]));
                const unsigned p1 = packbf2(ssp(d1[2]), ssp(d1[3]));
                unsigned q0 = __shfl(p0, s0, 64);
                unsigned q1 = __shfl(p1, s0, 64);
                unsigned q2 = __shfl(p0, s1, 64);
                unsigned q3 = __shfl(p1, s1, 64);
                if (g4 >= 2){ q0 = 0u; q1 = 0u; q2 = 0u; q3 = 0u; }
                union { unsigned u4[4]; short8 v; } bb;
                bb.u4[0]=q0; bb.u4[1]=q1; bb.u4[2]=q2; bb.u4[3]=q3;
                f32x4 d2 = __builtin_amdgcn_mfma_f32_16x16x32_bf16(a2[l], bb.v, c2[l], 0, 0, 0);
                float wk[4];
#pragma unroll
                for (int r = 0; r < 4; r++) wk[r] = ssp(d2[r]) * Yv[r];
#pragma unroll
                for (int off = 1; off < 8; off <<= 1)
#pragma unroll
                    for (int r = 0; r < 4; r++) wk[r] += __shfl_xor(wk[r], off, 64);
                if ((r16 & 7) == 0 && g4 < 2){
                    float* dst = l ? s_zn2 : s_zn1;
                    float4 st; st.x = wk[0]; st.y = wk[1]; st.z = wk[2]; st.w = wk[3];
                    *(float4*)&dst[i*NK + g4*4] = st;
                }
            }
        }
    }
    __syncthreads();

    // ================= per-batch sequential update =================
    // z1[i,k] = z1p[0] + z1p[1] + zn1
    if (t < NE*NK)
        s_z[t] = s_z1p[t] + s_z1p[NE*NK + t] + s_zn1[t];
    __syncthreads();
    // x1 = x0 + z1 @ gW0 + gb0   (512 threads: i = t>>4, e = t&15)
    {
        const int i = t >> 4, e = t & 15;
        float acc = gb[e];
#pragma unroll
        for (int k = 0; k < NK; k++)
            acc = fmaf(s_z[i*NK + k], gW[k*NEMB + e], acc);
        s_x[t] = X_emb[(i >> 4)*NEMB + e] + acc;
    }
    __syncthreads();
    // hx2 = ssp(x1 @ hW1 + hb1)
    if (t < NE*NK){
        const int i = t >> 3, k = t & 7;
        float acc = hb[NK + k];
#pragma unroll
        for (int e = 0; e < NEMB; e++)
            acc = fmaf(s_x[i*NEMB + e], hW[NEMB*NK + e*NK + k], acc);
        s_hx[t] = ssp(acc);
    }
    __syncthreads();
    // z2[i,k] = sum_j w2[i,j,k]*hx2[j,k]  (+ zn2)
    {
        const int i = t >> 4, j16 = t & 15;
        float zacc[NK];
#pragma unroll
        for (int k = 0; k < NK; k++) zacc[k] = 0.f;
#pragma unroll
        for (int qj = 0; qj < 2; qj++){
            const int j = qj*16 + j16;
            union { uint4 u; __hip_bfloat16 h[8]; } raw;
            raw.u = *(const uint4*)&s_w2[((size_t)i*NE + j)*NK];
            float pk[NK];
#pragma unroll
            for (int k = 0; k < NK; k++)
                pk[k] = __bfloat162float(raw.h[k]) * s_hx[j*NK + k];
#pragma unroll
            for (int off = 8; off > 0; off >>= 1)
#pragma unroll
                for (int k = 0; k < NK; k++) pk[k] += __shfl_down(pk[k], off, 16);
#pragma unroll
            for (int k = 0; k < NK; k++) zacc[k] += pk[k];
        }
        if (j16 == 0){
#pragma unroll
            for (int k = 0; k < NK; k++)
                s_z[i*NK + k] = zacc[k] + s_zn2[i*NK + k];
        }
    }
    __syncthreads();
    // x2 = x1 + z2 @ gW1 + gb1
    {
        const int i = t >> 4, e = t & 15;
        float acc = gb[NEMB + e];
#pragma unroll
        for (int k = 0; k < NK; k++)
            acc = fmaf(s_z[i*NK + k], gW[NK*NEMB + k*NEMB + e], acc);
        s_x[t] += acc;
    }
    __syncthreads();
    // readout: sum_i x2[i] @ orbW
    float part = s_x[t] * orbW[t & 15];
#pragma unroll
    for (int off = 32; off > 0; off >>= 1) part += __shfl_down(part, off, 64);
    if (lane == 0) s_red[wid] = part;
    __syncthreads();
    if (t == 0){
        float r = 0.f;
#pragma unroll
        for (int w = 0; w < 8; w++) r += s_red[w];
        out[b] = r;
    }
}

extern "C" void kernel_launch(void* const* d_in, const int* in_sizes, int n_in,
                              void* d_out, int out_size, void* d_ws, size_t ws_size,
                              hipStream_t stream)
{
    const float* edges_elec = (const float*)d_in[0];
    const float* edges_nuc  = (const float*)d_in[1];
    const float* X_emb      = (const float*)d_in[2];
    const float* Yk         = (const float*)d_in[3];
    const float* wW1        = (const float*)d_in[4];
    const float* wb1        = (const float*)d_in[5];
    const float* wW2        = (const float*)d_in[6];
    const float* wb2        = (const float*)d_in[7];
    const float* hW         = (const float*)d_in[8];
    const float* hb         = (const float*)d_in[9];
    const float* gW         = (const float*)d_in[10];
    const float* gb         = (const float*)d_in[11];
    const float* orbW       = (const float*)d_in[12];

    jastrow_kernel<<<NB, 512, 0, stream>>>(
        edges_elec, edges_nuc, X_emb, Yk, wW1, wb1, wW2, wb2, hW, hb,
        gW, gb, orbW, (float*)d_out);
}

// Round 3
// 154.224 us; speedup vs baseline: 1.0364x; 1.0126x over previous
//
#include <hip/hip_runtime.h>
#include <hip/hip_bf16.h>
#include <cstddef>
#include <cstdint>

// JastrowNet fully fused: ONE kernel, one block (1024 thr = 16 waves) per batch.
// Filter MLP (32->16->8, ssp) per 16-row tile:
//   MFMA-1: mfma_f32_16x16x32_bf16  D1 = W1^T x rows^T + b1
//           lane (g4,r16) holds h1[hidden=g4*4+r][row=r16]
//   MFMA-2: mfma_f32_16x16x16_bf16  (K=16 = hidden) -- the B-fragment layout
//           (k=g4*4+e, n=r16) is IDENTICAL to D1's fragment, so layer-2 needs
//           ZERO cross-lane shuffles: ssp(d1) -> 4 in-lane bf16 cvt -> B2.
//           A2[m=r16<8][k=g4*4+e] = W2[h][k_out], zero rows k_out>=8.
// Wave schedule (wid 0..15): even wid -> same-spin channel, odd -> anti,
// 4 tiles each ((wid>>1)*4..+3); all waves 1 nuclear tile (gp=wid).
// Layer-2 filters in LDS (16 KB); z1/zn in LDS; sequential update fused after
// one barrier. Workspace unused.

#define NB   512
#define NE   32
#define NA   8
#define NF   32
#define NH   16
#define NK   8
#define NEMB 16

typedef __attribute__((ext_vector_type(8))) short short8;
typedef __attribute__((ext_vector_type(4))) short short4b;
typedef __attribute__((ext_vector_type(4))) float f32x4;

__device__ __forceinline__ float ssp(float v){
    return fmaxf(v, 0.f) + __logf(1.f + __expf(-fabsf(v))) - 0.6931471805599453f;
}

// fp32 -> bf16 bits, round-to-nearest-even (finite inputs)
__device__ __forceinline__ short f2bf(float x){
    unsigned b = __float_as_uint(x);
    b += 0x7fffu + ((b >> 16) & 1u);
    return (short)(b >> 16);
}
__device__ __forceinline__ unsigned packbf2(float lo, float hi){
    return (unsigned)(unsigned short)f2bf(lo) | ((unsigned)(unsigned short)f2bf(hi) << 16);
}
__device__ __forceinline__ short8 cvt_row(float4 a, float4 b){
    short8 s;
    s[0]=f2bf(a.x); s[1]=f2bf(a.y); s[2]=f2bf(a.z); s[3]=f2bf(a.w);
    s[4]=f2bf(b.x); s[5]=f2bf(b.y); s[6]=f2bf(b.z); s[7]=f2bf(b.w);
    return s;
}

__device__ __forceinline__ f32x4 mfma16x16(short4b a, short4b b, f32x4 c){
#if __has_builtin(__builtin_amdgcn_mfma_f32_16x16x16bf16_1k)
    return __builtin_amdgcn_mfma_f32_16x16x16bf16_1k(a, b, c, 0, 0, 0);
#else
    f32x4 d;
    asm("s_nop 1\n\tv_mfma_f32_16x16x16_bf16 %0, %1, %2, %3\n\ts_nop 7"
        : "=v"(d) : "v"(a), "v"(b), "v"(c));
    return d;
#endif
}

extern "C" __global__ void __launch_bounds__(1024, 8)
jastrow_kernel(const float* __restrict__ edges_elec,
               const float* __restrict__ edges_nuc,
               const float* __restrict__ X_emb,
               const float* __restrict__ Yk,
               const float* __restrict__ wW1, const float* __restrict__ wb1,
               const float* __restrict__ wW2, const float* __restrict__ wb2,
               const float* __restrict__ hW,  const float* __restrict__ hb,
               const float* __restrict__ gW,  const float* __restrict__ gb,
               const float* __restrict__ orbW,
               float* __restrict__ out)
{
    __shared__ __align__(16) __hip_bfloat16 s_w2[NE*NE*NK];  // 16384 B
    __shared__ __align__(16) float s_z1p[2*NE*NK];           //  2048 B
    __shared__ __align__(16) float s_zn1[NE*NK];             //  1024 B
    __shared__ __align__(16) float s_zn2[NE*NK];             //  1024 B
    __shared__ float s_hx1[2*NK];
    __shared__ float s_x[NE*NEMB];                           //  2048 B
    __shared__ float s_z[NE*NK];                             //  1024 B
    __shared__ float s_hx[NE*NK];                            //  1024 B
    __shared__ float s_red[16];

    const int b = blockIdx.x, t = threadIdx.x;
    const int wid = t >> 6, lane = t & 63;
    const int r16 = lane & 15, g4 = lane >> 4;

    // ---- hx1[s][k] = ssp(X_emb[s] @ hW[0] + hb[0]) (spin-only) ----
    if (t < 2*NK){
        const int s = t >> 3, k = t & 7;
        float acc = hb[k];
#pragma unroll
        for (int e = 0; e < NEMB; e++)
            acc = fmaf(X_emb[s*NEMB + e], hW[e*NK + k], acc);
        s_hx1[t] = ssp(acc);
    }
    __syncthreads();

    // per-channel weight-fragment build (A1: x32 layout, A2: x16 layout)
    short8 a1[2]; short4b a2[2]; f32x4 c1[2], c2[2];
    auto build = [&](int cc){
#pragma unroll
        for (int l = 0; l < 2; l++){
            const float* W1 = wW1 + (size_t)(l*3 + cc)*NF*NH;
            const float* W2 = wW2 + (size_t)(l*3 + cc)*NH*NK;
            short8 s;
#pragma unroll
            for (int e = 0; e < 8; e++)
                s[e] = f2bf(W1[(g4*8 + e)*NH + r16]);
            a1[l] = s;
            short4b s2;
#pragma unroll
            for (int e = 0; e < 4; e++)
                s2[e] = (r16 < NK) ? f2bf(W2[(g4*4 + e)*NK + r16]) : (short)0;
            a2[l] = s2;
            const float* B1 = wb1 + (l*3 + cc)*NH;
            const float* B2 = wb2 + (l*3 + cc)*NK;
            f32x4 cb1, cb2;
#pragma unroll
            for (int r = 0; r < 4; r++){
                const int m = g4*4 + r;
                cb1[r] = B1[m];
                cb2[r] = (m < NK) ? B2[m] : 0.f;
            }
            c1[l] = cb1; c2[l] = cb2;
        }
    };

    // ---- electron channel for this wave: even wid -> cc=0, odd -> cc=1 ----
    const int ccE = wid & 1;
    const int wq  = (wid >> 1) * 4;
    build(ccE);
#pragma unroll
    for (int u = 0; u < 4; u++){
        const int tau = wq + u;
        const int qi = tau >> 4, g = tau & 15;
        const int qj = ccE ? (1 - qi) : qi;
        const int i  = qi*16 + g;
        const float* src = edges_elec
            + (((size_t)b*NE + i)*NE + qj*16 + r16)*NF + g4*8;
        const float4 ra = ((const float4*)src)[0];
        const float4 rb = ((const float4*)src)[1];
        const short8 bfr = cvt_row(ra, rb);
#pragma unroll
        for (int l = 0; l < 2; l++){
            f32x4 d1 = __builtin_amdgcn_mfma_f32_16x16x32_bf16(a1[l], bfr, c1[l], 0, 0, 0);
            short4b bb;
            bb[0] = f2bf(ssp(d1[0]));
            bb[1] = f2bf(ssp(d1[1]));
            bb[2] = f2bf(ssp(d1[2]));
            bb[3] = f2bf(ssp(d1[3]));
            f32x4 d2 = mfma16x16(a2[l], bb, c2[l]);
            float wk[4];
#pragma unroll
            for (int r = 0; r < 4; r++) wk[r] = ssp(d2[r]);
            if (ccE == 0 && r16 == g){
#pragma unroll
                for (int r = 0; r < 4; r++) wk[r] = 0.f;
            }
            if (l == 0){
                // z1 partial: sum over j (=r16), scale by hx1[spin(j)=qj]
#pragma unroll
                for (int off = 1; off < 16; off <<= 1)
#pragma unroll
                    for (int r = 0; r < 4; r++) wk[r] += __shfl_xor(wk[r], off, 64);
                if (r16 == 0 && g4 < 2){
                    float4 st;
                    st.x = wk[0]*s_hx1[qj*NK + g4*4 + 0];
                    st.y = wk[1]*s_hx1[qj*NK + g4*4 + 1];
                    st.z = wk[2]*s_hx1[qj*NK + g4*4 + 2];
                    st.w = wk[3]*s_hx1[qj*NK + g4*4 + 3];
                    *(float4*)&s_z1p[(qj*NE + i)*NK + g4*4] = st;
                }
            } else if (g4 < 2){
                const int j = qj*16 + r16;
                uint2 uu;
                uu.x = packbf2(wk[0], wk[1]);
                uu.y = packbf2(wk[2], wk[3]);
                *(uint2*)&s_w2[(i*NE + j)*NK + g4*4] = uu;
            }
        }
    }

    // ---- nuclear channel (all 16 waves, one tile each) ----
    {
        build(2);
        const int m = lane & 7;
        float Yv[4];
#pragma unroll
        for (int r = 0; r < 4; r++)
            Yv[r] = Yk[m*NK + ((g4*4 + r) & 7)];
        const int i = 2*wid + (r16 >> 3);
        const float* src = edges_nuc
            + (((size_t)b*NE + i)*NA + m)*NF + g4*8;
        const float4 ra = ((const float4*)src)[0];
        const float4 rb = ((const float4*)src)[1];
        const short8 bfr = cvt_row(ra, rb);
#pragma unroll
        for (int l = 0; l < 2; l++){
            f32x4 d1 = __builtin_amdgcn_mfma_f32_16x16x32_bf16(a1[l], bfr, c1[l], 0, 0, 0);
            short4b bb;
            bb[0] = f2bf(ssp(d1[0]));
            bb[1] = f2bf(ssp(d1[1]));
            bb[2] = f2bf(ssp(d1[2]));
            bb[3] = f2bf(ssp(d1[3]));
            f32x4 d2 = mfma16x16(a2[l], bb, c2[l]);
            float wk[4];
#pragma unroll
            for (int r = 0; r < 4; r++) wk[r] = ssp(d2[r]) * Yv[r];
#pragma unroll
            for (int off = 1; off < 8; off <<= 1)
#pragma unroll
                for (int r = 0; r < 4; r++) wk[r] += __shfl_xor(wk[r], off, 64);
            if ((r16 & 7) == 0 && g4 < 2){
                float* dst = l ? s_zn2 : s_zn1;
                float4 st; st.x = wk[0]; st.y = wk[1]; st.z = wk[2]; st.w = wk[3];
                *(float4*)&dst[i*NK + g4*4] = st;
            }
        }
    }
    __syncthreads();

    // ================= per-batch sequential update =================
    if (t < NE*NK)
        s_z[t] = s_z1p[t] + s_z1p[NE*NK + t] + s_zn1[t];
    __syncthreads();
    // x1 = x0 + z1 @ gW0 + gb0
    if (t < NE*NEMB){
        const int i = t >> 4, e = t & 15;
        float acc = gb[e];
#pragma unroll
        for (int k = 0; k < NK; k++)
            acc = fmaf(s_z[i*NK + k], gW[k*NEMB + e], acc);
        s_x[t] = X_emb[(i >> 4)*NEMB + e] + acc;
    }
    __syncthreads();
    // hx2 = ssp(x1 @ hW1 + hb1)
    if (t < NE*NK){
        const int i = t >> 3, k = t & 7;
        float acc = hb[NK + k];
#pragma unroll
        for (int e = 0; e < NEMB; e++)
            acc = fmaf(s_x[i*NEMB + e], hW[NEMB*NK + e*NK + k], acc);
        s_hx[t] = ssp(acc);
    }
    __syncthreads();
    // z2[i,k] = sum_j w2[i,j,k]*hx2[j,k]  (+ zn2)
    if (t < NE*NEMB){
        const int i = t >> 4, j16 = t & 15;
        float zacc[NK];
#pragma unroll
        for (int k = 0; k < NK; k++) zacc[k] = 0.f;
#pragma unroll
        for (int qj = 0; qj < 2; qj++){
            const int j = qj*16 + j16;
            union { uint4 u; __hip_bfloat16 h[8]; } raw;
            raw.u = *(const uint4*)&s_w2[((size_t)i*NE + j)*NK];
            float pk[NK];
#pragma unroll
            for (int k = 0; k < NK; k++)
                pk[k] = __bfloat162float(raw.h[k]) * s_hx[j*NK + k];
#pragma unroll
            for (int off = 8; off > 0; off >>= 1)
#pragma unroll
                for (int k = 0; k < NK; k++) pk[k] += __shfl_down(pk[k], off, 16);
#pragma unroll
            for (int k = 0; k < NK; k++) zacc[k] += pk[k];
        }
        if (j16 == 0){
#pragma unroll
            for (int k = 0; k < NK; k++)
                s_z[i*NK + k] = zacc[k] + s_zn2[i*NK + k];
        }
    }
    __syncthreads();
    // x2 = x1 + z2 @ gW1 + gb1
    if (t < NE*NEMB){
        const int i = t >> 4, e = t & 15;
        float acc = gb[NEMB + e];
#pragma unroll
        for (int k = 0; k < NK; k++)
            acc = fmaf(s_z[i*NK + k], gW[NK*NEMB + k*NEMB + e], acc);
        s_x[t] += acc;
    }
    __syncthreads();
    // readout: sum_i x2[i] @ orbW
    float part = (t < NE*NEMB) ? s_x[t] * orbW[t & 15] : 0.f;
#pragma unroll
    for (int off = 32; off > 0; off >>= 1) part += __shfl_down(part, off, 64);
    if (lane == 0) s_red[wid] = part;
    __syncthreads();
    if (t == 0){
        float r = 0.f;
#pragma unroll
        for (int w = 0; w < 16; w++) r += s_red[w];
        out[b] = r;
    }
}

extern "C" void kernel_launch(void* const* d_in, const int* in_sizes, int n_in,
                              void* d_out, int out_size, void* d_ws, size_t ws_size,
                              hipStream_t stream)
{
    const float* edges_elec = (const float*)d_in[0];
    const float* edges_nuc  = (const float*)d_in[1];
    const float* X_emb      = (const float*)d_in[2];
    const float* Yk         = (const float*)d_in[3];
    const float* wW1        = (const float*)d_in[4];
    const float* wb1        = (const float*)d_in[5];
    const float* wW2        = (const float*)d_in[6];
    const float* wb2        = (const float*)d_in[7];
    const float* hW         = (const float*)d_in[8];
    const float* hb         = (const float*)d_in[9];
    const float* gW         = (const float*)d_in[10];
    const float* gb         = (const float*)d_in[11];
    const float* orbW       = (const float*)d_in[12];

    jastrow_kernel<<<NB, 1024, 0, stream>>>(
        edges_elec, edges_nuc, X_emb, Yk, wW1, wb1, wW2, wb2, hW, hb,
        gW, gb, orbW, (float*)d_out);
}

// Round 4
// 152.630 us; speedup vs baseline: 1.0472x; 1.0104x over previous
//
#include <hip/hip_runtime.h>
#include <hip/hip_bf16.h>
#include <cstddef>
#include <cstdint>

// JastrowNet fully fused: ONE kernel, one block (1024 thr = 16 waves) per batch.
// Filter MLP (32->16->8, ssp) per 16-row tile:
//   MFMA-1: mfma_f32_16x16x32_bf16  D1 = W1^T x rows^T + b1
//           lane (g4,r16) holds h1[hidden=g4*4+r][row=r16]
//   MFMA-2: mfma_f32_16x16x16_bf16  (K=16 = hidden) -- the B-fragment layout
//           (k=g4*4+e, n=r16) is IDENTICAL to D1's fragment, so layer-2 needs
//           ZERO cross-lane shuffles: ssp(d1) -> 4 in-lane bf16 cvt -> B2.
// Wave schedule (wid 0..15): even wid -> same-spin channel, odd -> anti,
// 4 tiles each ((wid>>1)*4..+3); all waves 1 nuclear tile (gp=wid).
// Layer-2 filters in LDS (16 KB); z1/zn in LDS; sequential update fused after
// one barrier. Workspace unused.
//
// R3 post-mortem: __launch_bounds__(1024,8) capped VGPR at 32 -> scratch
// spills (WRITE_SIZE 34.8 MB of pure spill traffic). This round: (1024,4),
// VGPR cap 128 -- fragments stay in registers; at <=64 VGPR two blocks/CU
// still co-reside.

#define NB   512
#define NE   32
#define NA   8
#define NF   32
#define NH   16
#define NK   8
#define NEMB 16

typedef __attribute__((ext_vector_type(8))) short short8;
typedef __attribute__((ext_vector_type(4))) short short4b;
typedef __attribute__((ext_vector_type(4))) float f32x4;

__device__ __forceinline__ float ssp(float v){
    return fmaxf(v, 0.f) + __logf(1.f + __expf(-fabsf(v))) - 0.6931471805599453f;
}

// fp32 -> bf16 bits, round-to-nearest-even (finite inputs)
__device__ __forceinline__ short f2bf(float x){
    unsigned b = __float_as_uint(x);
    b += 0x7fffu + ((b >> 16) & 1u);
    return (short)(b >> 16);
}
__device__ __forceinline__ unsigned packbf2(float lo, float hi){
    return (unsigned)(unsigned short)f2bf(lo) | ((unsigned)(unsigned short)f2bf(hi) << 16);
}
__device__ __forceinline__ short8 cvt_row(float4 a, float4 b){
    short8 s;
    s[0]=f2bf(a.x); s[1]=f2bf(a.y); s[2]=f2bf(a.z); s[3]=f2bf(a.w);
    s[4]=f2bf(b.x); s[5]=f2bf(b.y); s[6]=f2bf(b.z); s[7]=f2bf(b.w);
    return s;
}

__device__ __forceinline__ f32x4 mfma16x16(short4b a, short4b b, f32x4 c){
#if __has_builtin(__builtin_amdgcn_mfma_f32_16x16x16bf16_1k)
    return __builtin_amdgcn_mfma_f32_16x16x16bf16_1k(a, b, c, 0, 0, 0);
#else
    f32x4 d;
    asm("s_nop 1\n\tv_mfma_f32_16x16x16_bf16 %0, %1, %2, %3\n\ts_nop 7"
        : "=v"(d) : "v"(a), "v"(b), "v"(c));
    return d;
#endif
}

extern "C" __global__ void __launch_bounds__(1024, 4)
jastrow_kernel(const float* __restrict__ edges_elec,
               const float* __restrict__ edges_nuc,
               const float* __restrict__ X_emb,
               const float* __restrict__ Yk,
               const float* __restrict__ wW1, const float* __restrict__ wb1,
               const float* __restrict__ wW2, const float* __restrict__ wb2,
               const float* __restrict__ hW,  const float* __restrict__ hb,
               const float* __restrict__ gW,  const float* __restrict__ gb,
               const float* __restrict__ orbW,
               float* __restrict__ out)
{
    __shared__ __align__(16) __hip_bfloat16 s_w2[NE*NE*NK];  // 16384 B
    __shared__ __align__(16) float s_z1p[2*NE*NK];           //  2048 B
    __shared__ __align__(16) float s_zn1[NE*NK];             //  1024 B
    __shared__ __align__(16) float s_zn2[NE*NK];             //  1024 B
    __shared__ float s_hx1[2*NK];
    __shared__ float s_x[NE*NEMB];                           //  2048 B
    __shared__ float s_z[NE*NK];                             //  1024 B
    __shared__ float s_hx[NE*NK];                            //  1024 B
    __shared__ float s_red[16];

    const int b = blockIdx.x, t = threadIdx.x;
    const int wid = t >> 6, lane = t & 63;
    const int r16 = lane & 15, g4 = lane >> 4;

    // ---- hx1[s][k] = ssp(X_emb[s] @ hW[0] + hb[0]) (spin-only) ----
    if (t < 2*NK){
        const int s = t >> 3, k = t & 7;
        float acc = hb[k];
#pragma unroll
        for (int e = 0; e < NEMB; e++)
            acc = fmaf(X_emb[s*NEMB + e], hW[e*NK + k], acc);
        s_hx1[t] = ssp(acc);
    }
    __syncthreads();

    // per-channel weight-fragment build (A1: x32 layout, A2: x16 layout)
    short8 a1[2]; short4b a2[2]; f32x4 c1[2], c2[2];
    auto build = [&](int cc){
#pragma unroll
        for (int l = 0; l < 2; l++){
            const float* W1 = wW1 + (size_t)(l*3 + cc)*NF*NH;
            const float* W2 = wW2 + (size_t)(l*3 + cc)*NH*NK;
            short8 s;
#pragma unroll
            for (int e = 0; e < 8; e++)
                s[e] = f2bf(W1[(g4*8 + e)*NH + r16]);
            a1[l] = s;
            short4b s2;
#pragma unroll
            for (int e = 0; e < 4; e++)
                s2[e] = (r16 < NK) ? f2bf(W2[(g4*4 + e)*NK + r16]) : (short)0;
            a2[l] = s2;
            const float* B1 = wb1 + (l*3 + cc)*NH;
            const float* B2 = wb2 + (l*3 + cc)*NK;
            f32x4 cb1, cb2;
#pragma unroll
            for (int r = 0; r < 4; r++){
                const int m = g4*4 + r;
                cb1[r] = B1[m];
                cb2[r] = (m < NK) ? B2[m] : 0.f;
            }
            c1[l] = cb1; c2[l] = cb2;
        }
    };

    // ---- electron channel for this wave: even wid -> cc=0, odd -> cc=1 ----
    const int ccE = wid & 1;
    const int wq  = (wid >> 1) * 4;
    build(ccE);
#pragma unroll
    for (int u = 0; u < 4; u++){
        const int tau = wq + u;
        const int qi = tau >> 4, g = tau & 15;
        const int qj = ccE ? (1 - qi) : qi;
        const int i  = qi*16 + g;
        const float* src = edges_elec
            + (((size_t)b*NE + i)*NE + qj*16 + r16)*NF + g4*8;
        const float4 ra = ((const float4*)src)[0];
        const float4 rb = ((const float4*)src)[1];
        const short8 bfr = cvt_row(ra, rb);
#pragma unroll
        for (int l = 0; l < 2; l++){
            f32x4 d1 = __builtin_amdgcn_mfma_f32_16x16x32_bf16(a1[l], bfr, c1[l], 0, 0, 0);
            short4b bb;
            bb[0] = f2bf(ssp(d1[0]));
            bb[1] = f2bf(ssp(d1[1]));
            bb[2] = f2bf(ssp(d1[2]));
            bb[3] = f2bf(ssp(d1[3]));
            f32x4 d2 = mfma16x16(a2[l], bb, c2[l]);
            float wk[4];
#pragma unroll
            for (int r = 0; r < 4; r++) wk[r] = ssp(d2[r]);
            if (ccE == 0 && r16 == g){
#pragma unroll
                for (int r = 0; r < 4; r++) wk[r] = 0.f;
            }
            if (l == 0){
                // z1 partial: sum over j (=r16), scale by hx1[spin(j)=qj]
#pragma unroll
                for (int off = 1; off < 16; off <<= 1)
#pragma unroll
                    for (int r = 0; r < 4; r++) wk[r] += __shfl_xor(wk[r], off, 64);
                if (r16 == 0 && g4 < 2){
                    float4 st;
                    st.x = wk[0]*s_hx1[qj*NK + g4*4 + 0];
                    st.y = wk[1]*s_hx1[qj*NK + g4*4 + 1];
                    st.z = wk[2]*s_hx1[qj*NK + g4*4 + 2];
                    st.w = wk[3]*s_hx1[qj*NK + g4*4 + 3];
                    *(float4*)&s_z1p[(qj*NE + i)*NK + g4*4] = st;
                }
            } else if (g4 < 2){
                const int j = qj*16 + r16;
                uint2 uu;
                uu.x = packbf2(wk[0], wk[1]);
                uu.y = packbf2(wk[2], wk[3]);
                *(uint2*)&s_w2[(i*NE + j)*NK + g4*4] = uu;
            }
        }
    }

    // ---- nuclear channel (all 16 waves, one tile each) ----
    {
        build(2);
        const int m = lane & 7;
        float Yv[4];
#pragma unroll
        for (int r = 0; r < 4; r++)
            Yv[r] = Yk[m*NK + ((g4*4 + r) & 7)];
        const int i = 2*wid + (r16 >> 3);
        const float* src = edges_nuc
            + (((size_t)b*NE + i)*NA + m)*NF + g4*8;
        const float4 ra = ((const float4*)src)[0];
        const float4 rb = ((const float4*)src)[1];
        const short8 bfr = cvt_row(ra, rb);
#pragma unroll
        for (int l = 0; l < 2; l++){
            f32x4 d1 = __builtin_amdgcn_mfma_f32_16x16x32_bf16(a1[l], bfr, c1[l], 0, 0, 0);
            short4b bb;
            bb[0] = f2bf(ssp(d1[0]));
            bb[1] = f2bf(ssp(d1[1]));
            bb[2] = f2bf(ssp(d1[2]));
            bb[3] = f2bf(ssp(d1[3]));
            f32x4 d2 = mfma16x16(a2[l], bb, c2[l]);
            float wk[4];
#pragma unroll
            for (int r = 0; r < 4; r++) wk[r] = ssp(d2[r]) * Yv[r];
#pragma unroll
            for (int off = 1; off < 8; off <<= 1)
#pragma unroll
                for (int r = 0; r < 4; r++) wk[r] += __shfl_xor(wk[r], off, 64);
            if ((r16 & 7) == 0 && g4 < 2){
                float* dst = l ? s_zn2 : s_zn1;
                float4 st; st.x = wk[0]; st.y = wk[1]; st.z = wk[2]; st.w = wk[3];
                *(float4*)&dst[i*NK + g4*4] = st;
            }
        }
    }
    __syncthreads();

    // ================= per-batch sequential update =================
    if (t < NE*NK)
        s_z[t] = s_z1p[t] + s_z1p[NE*NK + t] + s_zn1[t];
    __syncthreads();
    // x1 = x0 + z1 @ gW0 + gb0
    if (t < NE*NEMB){
        const int i = t >> 4, e = t & 15;
        float acc = gb[e];
#pragma unroll
        for (int k = 0; k < NK; k++)
            acc = fmaf(s_z[i*NK + k], gW[k*NEMB + e], acc);
        s_x[t] = X_emb[(i >> 4)*NEMB + e] + acc;
    }
    __syncthreads();
    // hx2 = ssp(x1 @ hW1 + hb1)
    if (t < NE*NK){
        const int i = t >> 3, k = t & 7;
        float acc = hb[NK + k];
#pragma unroll
        for (int e = 0; e < NEMB; e++)
            acc = fmaf(s_x[i*NEMB + e], hW[NEMB*NK + e*NK + k], acc);
        s_hx[t] = ssp(acc);
    }
    __syncthreads();
    // z2[i,k] = sum_j w2[i,j,k]*hx2[j,k]  (+ zn2)
    if (t < NE*NEMB){
        const int i = t >> 4, j16 = t & 15;
        float zacc[NK];
#pragma unroll
        for (int k = 0; k < NK; k++) zacc[k] = 0.f;
#pragma unroll
        for (int qj = 0; qj < 2; qj++){
            const int j = qj*16 + j16;
            union { uint4 u; __hip_bfloat16 h[8]; } raw;
            raw.u = *(const uint4*)&s_w2[((size_t)i*NE + j)*NK];
            float pk[NK];
#pragma unroll
            for (int k = 0; k < NK; k++)
                pk[k] = __bfloat162float(raw.h[k]) * s_hx[j*NK + k];
#pragma unroll
            for (int off = 8; off > 0; off >>= 1)
#pragma unroll
                for (int k = 0; k < NK; k++) pk[k] += __shfl_down(pk[k], off, 16);
#pragma unroll
            for (int k = 0; k < NK; k++) zacc[k] += pk[k];
        }
        if (j16 == 0){
#pragma unroll
            for (int k = 0; k < NK; k++)
                s_z[i*NK + k] = zacc[k] + s_zn2[i*NK + k];
        }
    }
    __syncthreads();
    // x2 = x1 + z2 @ gW1 + gb1
    if (t < NE*NEMB){
        const int i = t >> 4, e = t & 15;
        float acc = gb[NEMB + e];
#pragma unroll
        for (int k = 0; k < NK; k++)
            acc = fmaf(s_z[i*NK + k], gW[NK*NEMB + k*NEMB + e], acc);
        s_x[t] += acc;
    }
    __syncthreads();
    // readout: sum_i x2[i] @ orbW
    float part = (t < NE*NEMB) ? s_x[t] * orbW[t & 15] : 0.f;
#pragma unroll
    for (int off = 32; off > 0; off >>= 1) part += __shfl_down(part, off, 64);
    if (lane == 0) s_red[wid] = part;
    __syncthreads();
    if (t == 0){
        float r = 0.f;
#pragma unroll
        for (int w = 0; w < 16; w++) r += s_red[w];
        out[b] = r;
    }
}

extern "C" void kernel_launch(void* const* d_in, const int* in_sizes, int n_in,
                              void* d_out, int out_size, void* d_ws, size_t ws_size,
                              hipStream_t stream)
{
    const float* edges_elec = (const float*)d_in[0];
    const float* edges_nuc  = (const float*)d_in[1];
    const float* X_emb      = (const float*)d_in[2];
    const float* Yk         = (const float*)d_in[3];
    const float* wW1        = (const float*)d_in[4];
    const float* wb1        = (const float*)d_in[5];
    const float* wW2        = (const float*)d_in[6];
    const float* wb2        = (const float*)d_in[7];
    const float* hW         = (const float*)d_in[8];
    const float* hb         = (const float*)d_in[9];
    const float* gW         = (const float*)d_in[10];
    const float* gb         = (const float*)d_in[11];
    const float* orbW       = (const float*)d_in[12];

    jastrow_kernel<<<NB, 1024, 0, stream>>>(
        edges_elec, edges_nuc, X_emb, Yk, wW1, wb1, wW2, wb2, hW, hb,
        gW, gb, orbW, (float*)d_out);
}

// Round 7
// 148.957 us; speedup vs baseline: 1.0730x; 1.0247x over previous
//
#include <hip/hip_runtime.h>
#include <hip/hip_bf16.h>
#include <cstddef>
#include <cstdint>

// JastrowNet fully fused: ONE kernel, one block (1024 thr = 16 waves) per batch.
// Filter MLP (32->16->8, ssp) per 16-row tile:
//   MFMA-1: mfma_f32_16x16x32_bf16  D1 = W1^T x rows^T + b1
//           lane (g4,r16) holds h1[hidden=g4*4+r][row=r16]
//   MFMA-2: mfma_f32_16x16x16_bf16  (K=16 = hidden) -- B-fragment layout is
//           IDENTICAL to D1's D-fragment: ssp(d1) -> 4 in-lane cvt -> B2.
// Wave schedule (wid 0..15): even wid -> same-spin, odd -> anti, 4 tiles each;
// all waves 1 nuclear tile.
// R6 post-mortem: NaN output. Suspects: inline-asm v_cvt_pk_bf16_f32 used for
// ALL conversions incl. weight fragments (wrong pack semantics -> garbage bf16
// -> NaN through MFMA), or amdgcn exp2/log builtins. R7 reverts BOTH to R4's
// proven paths (integer RNE f2bf; __expf/__logf ssp, simplified to 4 ops) and
// keeps the scheduling wins (nuc hoist, depth-1 pipeline with no uninit reads,
// folded z1 barrier).  Workspace unused.

#define NB   512
#define NE   32
#define NA   8
#define NF   32
#define NH   16
#define NK   8
#define NEMB 16

typedef __attribute__((ext_vector_type(8))) short short8;
typedef __attribute__((ext_vector_type(4))) short short4b;
typedef __attribute__((ext_vector_type(4))) float f32x4;

#define LN2 0.69314718055994530942f

// ssp(v) = softplus(v) - ln2; inputs here are bounded (|v| < ~20) so the
// direct form is safe: __expf overflows only past ~88.
__device__ __forceinline__ float ssp(float v){
    return __logf(1.f + __expf(v)) - LN2;
}

// fp32 -> bf16 bits, round-to-nearest-even (finite inputs) -- R4-proven
__device__ __forceinline__ short f2bf(float x){
    unsigned b = __float_as_uint(x);
    b += 0x7fffu + ((b >> 16) & 1u);
    return (short)(b >> 16);
}
__device__ __forceinline__ unsigned packbf2(float lo, float hi){
    return (unsigned)(unsigned short)f2bf(lo) | ((unsigned)(unsigned short)f2bf(hi) << 16);
}
__device__ __forceinline__ short8 cvt_row(float4 a, float4 b){
    short8 s;
    s[0]=f2bf(a.x); s[1]=f2bf(a.y); s[2]=f2bf(a.z); s[3]=f2bf(a.w);
    s[4]=f2bf(b.x); s[5]=f2bf(b.y); s[6]=f2bf(b.z); s[7]=f2bf(b.w);
    return s;
}

__device__ __forceinline__ f32x4 mfma16x16(short4b a, short4b b, f32x4 c){
#if __has_builtin(__builtin_amdgcn_mfma_f32_16x16x16bf16_1k)
    return __builtin_amdgcn_mfma_f32_16x16x16bf16_1k(a, b, c, 0, 0, 0);
#else
    f32x4 d;
    asm("s_nop 1\n\tv_mfma_f32_16x16x16_bf16 %0, %1, %2, %3\n\ts_nop 7"
        : "=v"(d) : "v"(a), "v"(b), "v"(c));
    return d;
#endif
}

extern "C" __global__ void __launch_bounds__(1024, 4)
jastrow_kernel(const float* __restrict__ edges_elec,
               const float* __restrict__ edges_nuc,
               const float* __restrict__ X_emb,
               const float* __restrict__ Yk,
               const float* __restrict__ wW1, const float* __restrict__ wb1,
               const float* __restrict__ wW2, const float* __restrict__ wb2,
               const float* __restrict__ hW,  const float* __restrict__ hb,
               const float* __restrict__ gW,  const float* __restrict__ gb,
               const float* __restrict__ orbW,
               float* __restrict__ out)
{
    __shared__ __align__(16) __hip_bfloat16 s_w2[NE*NE*NK];  // 16384 B
    __shared__ __align__(16) float s_z1p[2*NE*NK];           //  2048 B
    __shared__ __align__(16) float s_zn1[NE*NK];             //  1024 B
    __shared__ __align__(16) float s_zn2[NE*NK];             //  1024 B
    __shared__ float s_hx1[2*NK];
    __shared__ float s_x[NE*NEMB];                           //  2048 B
    __shared__ float s_z[NE*NK];                             //  1024 B
    __shared__ float s_hx[NE*NK];                            //  1024 B
    __shared__ float s_red[16];

    const int b = blockIdx.x, t = threadIdx.x;
    const int wid = t >> 6, lane = t & 63;
    const int r16 = lane & 15, g4 = lane >> 4;

    // ---- hx1[s][k] = ssp(X_emb[s] @ hW[0] + hb[0]) (spin-only) ----
    if (t < 2*NK){
        const int s = t >> 3, k = t & 7;
        float acc = hb[k];
#pragma unroll
        for (int e = 0; e < NEMB; e++)
            acc = fmaf(X_emb[s*NEMB + e], hW[e*NK + k], acc);
        s_hx1[t] = ssp(acc);
    }
    __syncthreads();

    // per-channel weight-fragment build (A1: x32 layout, A2: x16 layout)
    short8 a1[2]; short4b a2[2]; f32x4 c1[2], c2[2];
    auto build = [&](int cc){
#pragma unroll
        for (int l = 0; l < 2; l++){
            const float* W1 = wW1 + (size_t)(l*3 + cc)*NF*NH;
            const float* W2 = wW2 + (size_t)(l*3 + cc)*NH*NK;
            short8 s;
#pragma unroll
            for (int e = 0; e < 8; e++)
                s[e] = f2bf(W1[(g4*8 + e)*NH + r16]);
            a1[l] = s;
            short4b s2;
#pragma unroll
            for (int e = 0; e < 4; e++)
                s2[e] = (r16 < NK) ? f2bf(W2[(g4*4 + e)*NK + r16]) : (short)0;
            a2[l] = s2;
            const float* B1 = wb1 + (l*3 + cc)*NH;
            const float* B2 = wb2 + (l*3 + cc)*NK;
            f32x4 cb1, cb2;
#pragma unroll
            for (int r = 0; r < 4; r++){
                const int m = g4*4 + r;
                cb1[r] = B1[m];
                cb2[r] = (m < NK) ? B2[m] : 0.f;
            }
            c1[l] = cb1; c2[l] = cb2;
        }
    };

    // ---- hoist nuclear-tile loads (independent of elec phase) ----
    const int nm = lane & 7;
    const int ni = 2*wid + (r16 >> 3);
    const float* nsrc = edges_nuc + (((size_t)b*NE + ni)*NA + nm)*NF + g4*8;
    const float4 nra = ((const float4*)nsrc)[0];
    const float4 nrb = ((const float4*)nsrc)[1];

    // ---- electron channel: even wid -> cc=0 (same), odd -> cc=1 (anti) ----
    const int ccE = wid & 1;
    const int wq  = (wid >> 1) * 4;
    build(ccE);

    auto esrc = [&](int u) -> const float* {
        const int tau = wq + u;
        const int qi = tau >> 4, g = tau & 15;
        const int qj = ccE ? (1 - qi) : qi;
        return edges_elec + (((size_t)b*NE + qi*16 + g)*NE + qj*16 + r16)*NF + g4*8;
    };

    float4 ra = ((const float4*)esrc(0))[0];
    float4 rb = ((const float4*)esrc(0))[1];
#pragma unroll
    for (int u = 0; u < 4; u++){
        float4 nxa = ra, nxb = rb;           // defined at u==3 (self; dead after)
        if (u < 3){
            const float* src = esrc(u + 1);
            nxa = ((const float4*)src)[0];
            nxb = ((const float4*)src)[1];
        }
        const int tau = wq + u;
        const int qi = tau >> 4, g = tau & 15;
        const int qj = ccE ? (1 - qi) : qi;
        const int i  = qi*16 + g;
        const short8 bfr = cvt_row(ra, rb);
#pragma unroll
        for (int l = 0; l < 2; l++){
            f32x4 d1 = __builtin_amdgcn_mfma_f32_16x16x32_bf16(a1[l], bfr, c1[l], 0, 0, 0);
            short4b bb;
            bb[0] = f2bf(ssp(d1[0]));
            bb[1] = f2bf(ssp(d1[1]));
            bb[2] = f2bf(ssp(d1[2]));
            bb[3] = f2bf(ssp(d1[3]));
            f32x4 d2 = mfma16x16(a2[l], bb, c2[l]);
            float wk[4];
#pragma unroll
            for (int r = 0; r < 4; r++) wk[r] = ssp(d2[r]);
            if (ccE == 0 && r16 == g){
#pragma unroll
                for (int r = 0; r < 4; r++) wk[r] = 0.f;
            }
            if (l == 0){
                // z1 partial: sum over j (=r16), scale by hx1[spin(j)=qj]
#pragma unroll
                for (int off = 1; off < 16; off <<= 1)
#pragma unroll
                    for (int r = 0; r < 4; r++) wk[r] += __shfl_xor(wk[r], off, 64);
                if (r16 == 0 && g4 < 2){
                    float4 st;
                    st.x = wk[0]*s_hx1[qj*NK + g4*4 + 0];
                    st.y = wk[1]*s_hx1[qj*NK + g4*4 + 1];
                    st.z = wk[2]*s_hx1[qj*NK + g4*4 + 2];
                    st.w = wk[3]*s_hx1[qj*NK + g4*4 + 3];
                    *(float4*)&s_z1p[(qj*NE + i)*NK + g4*4] = st;
                }
            } else if (g4 < 2){
                const int j = qj*16 + r16;
                uint2 uu;
                uu.x = packbf2(wk[0], wk[1]);
                uu.y = packbf2(wk[2], wk[3]);
                *(uint2*)&s_w2[(i*NE + j)*NK + g4*4] = uu;
            }
        }
        ra = nxa; rb = nxb;
    }

    // ---- nuclear channel (all 16 waves, one tile each; loads hoisted) ----
    {
        build(2);
        float Yv[4];
#pragma unroll
        for (int r = 0; r < 4; r++)
            Yv[r] = Yk[nm*NK + ((g4*4 + r) & 7)];
        const short8 bfr = cvt_row(nra, nrb);
#pragma unroll
        for (int l = 0; l < 2; l++){
            f32x4 d1 = __builtin_amdgcn_mfma_f32_16x16x32_bf16(a1[l], bfr, c1[l], 0, 0, 0);
            short4b bb;
            bb[0] = f2bf(ssp(d1[0]));
            bb[1] = f2bf(ssp(d1[1]));
            bb[2] = f2bf(ssp(d1[2]));
            bb[3] = f2bf(ssp(d1[3]));
            f32x4 d2 = mfma16x16(a2[l], bb, c2[l]);
            float wk[4];
#pragma unroll
            for (int r = 0; r < 4; r++) wk[r] = ssp(d2[r]) * Yv[r];
#pragma unroll
            for (int off = 1; off < 8; off <<= 1)
#pragma unroll
                for (int r = 0; r < 4; r++) wk[r] += __shfl_xor(wk[r], off, 64);
            if ((r16 & 7) == 0 && g4 < 2){
                float* dst = l ? s_zn2 : s_zn1;
                float4 st; st.x = wk[0]; st.y = wk[1]; st.z = wk[2]; st.w = wk[3];
                *(float4*)&dst[ni*NK + g4*4] = st;
            }
        }
    }
    __syncthreads();

    // ================= per-batch sequential update =================
    // x1 = x0 + z1 @ gW0 + gb0   (z1 folded inline: z1p halves + zn1)
    if (t < NE*NEMB){
        const int i = t >> 4, e = t & 15;
        float acc = gb[e];
#pragma unroll
        for (int k = 0; k < NK; k++){
            const float zk = s_z1p[i*NK + k] + s_z1p[NE*NK + i*NK + k]
                           + s_zn1[i*NK + k];
            acc = fmaf(zk, gW[k*NEMB + e], acc);
        }
        s_x[t] = X_emb[(i >> 4)*NEMB + e] + acc;
    }
    __syncthreads();
    // hx2 = ssp(x1 @ hW1 + hb1)
    if (t < NE*NK){
        const int i = t >> 3, k = t & 7;
        float acc = hb[NK + k];
#pragma unroll
        for (int e = 0; e < NEMB; e++)
            acc = fmaf(s_x[i*NEMB + e], hW[NEMB*NK + e*NK + k], acc);
        s_hx[t] = ssp(acc);
    }
    __syncthreads();
    // z2[i,k] = sum_j w2[i,j,k]*hx2[j,k]  (+ zn2)
    if (t < NE*NEMB){
        const int i = t >> 4, j16 = t & 15;
        float zacc[NK];
#pragma unroll
        for (int k = 0; k < NK; k++) zacc[k] = 0.f;
#pragma unroll
        for (int qj = 0; qj < 2; qj++){
            const int j = qj*16 + j16;
            union { uint4 u; __hip_bfloat16 h[8]; } raw;
            raw.u = *(const uint4*)&s_w2[((size_t)i*NE + j)*NK];
            float pk[NK];
#pragma unroll
            for (int k = 0; k < NK; k++)
                pk[k] = __bfloat162float(raw.h[k]) * s_hx[j*NK + k];
#pragma unroll
            for (int off = 8; off > 0; off >>= 1)
#pragma unroll
                for (int k = 0; k < NK; k++) pk[k] += __shfl_down(pk[k], off, 16);
#pragma unroll
            for (int k = 0; k < NK; k++) zacc[k] += pk[k];
        }
        if (j16 == 0){
#pragma unroll
            for (int k = 0; k < NK; k++)
                s_z[i*NK + k] = zacc[k] + s_zn2[i*NK + k];
        }
    }
    __syncthreads();
    // x2 = x1 + z2 @ gW1 + gb1
    if (t < NE*NEMB){
        const int i = t >> 4, e = t & 15;
        float acc = gb[NEMB + e];
#pragma unroll
        for (int k = 0; k < NK; k++)
            acc = fmaf(s_z[i*NK + k], gW[NK*NEMB + k*NEMB + e], acc);
        s_x[t] += acc;
    }
    __syncthreads();
    // readout: sum_i x2[i] @ orbW
    float part = (t < NE*NEMB) ? s_x[t] * orbW[t & 15] : 0.f;
#pragma unroll
    for (int off = 32; off > 0; off >>= 1) part += __shfl_down(part, off, 64);
    if (lane == 0) s_red[wid] = part;
    __syncthreads();
    if (t == 0){
        float r = 0.f;
#pragma unroll
        for (int w = 0; w < 16; w++) r += s_red[w];
        out[b] = r;
    }
}

extern "C" void kernel_launch(void* const* d_in, const int* in_sizes, int n_in,
                              void* d_out, int out_size, void* d_ws, size_t ws_size,
                              hipStream_t stream)
{
    const float* edges_elec = (const float*)d_in[0];
    const float* edges_nuc  = (const float*)d_in[1];
    const float* X_emb      = (const float*)d_in[2];
    const float* Yk         = (const float*)d_in[3];
    const float* wW1        = (const float*)d_in[4];
    const float* wb1        = (const float*)d_in[5];
    const float* wW2        = (const float*)d_in[6];
    const float* wb2        = (const float*)d_in[7];
    const float* hW         = (const float*)d_in[8];
    const float* hb         = (const float*)d_in[9];
    const float* gW         = (const float*)d_in[10];
    const float* gb         = (const float*)d_in[11];
    const float* orbW       = (const float*)d_in[12];

    jastrow_kernel<<<NB, 1024, 0, stream>>>(
        edges_elec, edges_nuc, X_emb, Yk, wW1, wb1, wW2, wb2, hW, hb,
        gW, gb, orbW, (float*)d_out);
}